// Round 2
// baseline (277.341 us; speedup 1.0000x reference)
//
#include <hip/hip_runtime.h>
#include <hip/hip_bf16.h>
#include <stdint.h>

// LORI_FC: out = blockdiag(x; D) + (x @ Wl^T) @ Wr^T + b_right + bias
// M=8192 tokens, IN=OUT=4096, RANK=64, 64 blocks of 64x64.
//
// R3: fuse K1+K2 -> single kernel reading x ONCE (268 MB floor ~43 us).
// Key insight: wave w's feature slice [1024w,1024w+1024) is exactly the x
// input needed by output blocks nb in [16w,16w+16) (block-diagonal structure),
// so x stays register-resident per wave; only t (16x64) crosses waves via LDS.
// R4: non-temporal hints on the streaming tensors (x loads, out stores) —
// both touched exactly once; keeps wl_pack/bp_pack (1.5 MiB, re-read by all
// 512 wgs = ~512 MiB L2 read traffic) resident in L2 instead of being
// evicted by the 256 MiB of streaming traffic.
// R5: fix compile — nontemporal builtins need clang ext_vector types, not
// HIP_vector_type float4; use floatx4 throughout the load path.

#define M_TOT   8192
#define IN_F    4096
#define OUT_F   4096
#define RANK    64
#define NBLK    64

typedef __attribute__((ext_vector_type(8))) short  bf16x8;
typedef __attribute__((ext_vector_type(4))) float  floatx4;

// ---- ws layout (bytes) ----
#define WS_BIAS   0            // fp32[4096]                     : b_right + bias
#define WS_WL     16384        // bf16 [128 kc][64 n][32 k]      : Wl^T B-frag packed
#define WS_BP     540672       // bf16 [64 nb][4 kc][64 n][32 k] : [D;Wr^T] B-frag packed

#define S_TP 68                // t_part LDS row stride (floats); 272B = 17x16B aligned

__device__ __forceinline__ unsigned short f2bf(float f) {
    union { float f; unsigned int u; } v; v.f = f;
    unsigned int u = v.u;
    u += 0x7fffu + ((u >> 16) & 1u);   // round-to-nearest-even
    return (unsigned short)(u >> 16);
}

__device__ __forceinline__ bf16x8 cvt8(floatx4 a0, floatx4 a1) {
    bf16x8 af;
    af[0] = (short)f2bf(a0[0]); af[1] = (short)f2bf(a0[1]);
    af[2] = (short)f2bf(a0[2]); af[3] = (short)f2bf(a0[3]);
    af[4] = (short)f2bf(a1[0]); af[5] = (short)f2bf(a1[1]);
    af[6] = (short)f2bf(a1[2]); af[7] = (short)f2bf(a1[3]);
    return af;
}

// ---------------- prep: pack weights to bf16 in MFMA fragment order -------------
__global__ __launch_bounds__(256) void prep_kernel(
    const float* __restrict__ diag, const float* __restrict__ Wl,
    const float* __restrict__ Wr,   const float* __restrict__ br,
    const float* __restrict__ bias,
    float* __restrict__ bias_comb, unsigned short* __restrict__ wl_pack,
    unsigned short* __restrict__ bp_pack)
{
    int tid = blockIdx.x * blockDim.x + threadIdx.x;
    int nthr = gridDim.x * blockDim.x;

    for (int i = tid; i < OUT_F; i += nthr)
        bias_comb[i] = br[i] + bias[i];

    // Wl[n][c] -> wl_pack[((c>>5)*64 + n)*32 + (c&31)]
    for (int i = tid; i < 64 * 4096; i += nthr) {
        int n = i >> 12, c = i & 4095;
        wl_pack[((size_t)(c >> 5) * 64 + n) * 32 + (c & 31)] = f2bf(Wl[i]);
    }

    // diag[nb][k][n] -> bp_pack[((nb*4 + (k>>5))*64 + n)*32 + (k&31)]
    for (int i = tid; i < 64 * 64 * 64; i += nthr) {
        int nb = i >> 12, k = (i >> 6) & 63, n = i & 63;
        bp_pack[(((size_t)nb * 4 + (k >> 5)) * 64 + n) * 32 + (k & 31)] = f2bf(diag[i]);
    }

    // Wr[nb*64+n][r], concat-k = 64+r -> bp_pack[...]
    for (int i = tid; i < 64 * 64 * 64; i += nthr) {
        int nb = i >> 12, n = (i >> 6) & 63, r = i & 63;
        int kt = 64 + r;
        bp_pack[(((size_t)nb * 4 + (kt >> 5)) * 64 + n) * 32 + (kt & 31)] = f2bf(Wr[i]);
    }
}

// ---------------- fused: t = x@Wl^T (LDS-reduced), out = [x|t]@[D;Wr^T]+bias ----
// 512 workgroups x 4 waves. wg = 16-token m-tile; wave w owns features
// [1024w, 1024w+1024) and output blocks [16w, 16w+16).
__global__ __launch_bounds__(256, 2) void fused_kernel(
    const float* __restrict__ x, const unsigned short* __restrict__ wl_pack,
    const unsigned short* __restrict__ bp_pack, const float* __restrict__ bias_comb,
    float* __restrict__ out)
{
    __shared__ float t_part[4 * 16 * S_TP];   // [wave][m][rank], padded

    int w = threadIdx.x >> 6;       // wave 0..3
    int lane = threadIdx.x & 63;
    int q = lane >> 4, l = lane & 15;
    int mt = blockIdx.x;            // 0..511
    int m0 = mt * 16;
    int kc_g0 = w * 32;             // this wave's first k-chunk (32 feats each)

    const float* xrow = x + (size_t)(m0 + l) * IN_F + q * 8;

    // ---- Phase A: load x slice into registers (A-frag layout), accumulate t ----
    bf16x8 xfrag[32];               // 16 tokens x 1024 features bf16 = 128 VGPRs
    floatx4 tacc[4] = {};           // t partial: 16 tokens x 64 ranks

    #pragma unroll
    for (int kc = 0; kc < 32; ++kc) {
        int kc_g = kc_g0 + kc;
        const float* ap = xrow + kc_g * 32;
        floatx4 a0 = __builtin_nontemporal_load((const floatx4*)(ap));
        floatx4 a1 = __builtin_nontemporal_load((const floatx4*)(ap + 4));
        bf16x8 af = cvt8(a0, a1);
        xfrag[kc] = af;
        #pragma unroll
        for (int nt = 0; nt < 4; ++nt) {
            bf16x8 bf = *(const bf16x8*)(wl_pack + ((size_t)(kc_g * 64 + nt * 16 + l) * 32 + q * 8));
            tacc[nt] = __builtin_amdgcn_mfma_f32_16x16x32_bf16(af, bf, tacc[nt], 0, 0, 0);
        }
    }

    // write t partial to LDS: C/D layout m=q*4+r, n=nt*16+l  (2-way bank alias max)
    #pragma unroll
    for (int nt = 0; nt < 4; ++nt)
        #pragma unroll
        for (int r = 0; r < 4; ++r)
            t_part[w * 16 * S_TP + (q * 4 + r) * S_TP + nt * 16 + l] = tacc[nt][r];

    __syncthreads();

    // ---- reduce t across waves, build A-frags: t[m=l][k=kc2*32+q*8+j] ----
    bf16x8 tfrag[2];
    #pragma unroll
    for (int kc2 = 0; kc2 < 2; ++kc2) {
        floatx4 s0 = {0.f, 0.f, 0.f, 0.f}, s1 = {0.f, 0.f, 0.f, 0.f};
        #pragma unroll
        for (int p = 0; p < 4; ++p) {
            const float* tp = &t_part[p * 16 * S_TP + l * S_TP + kc2 * 32 + q * 8];
            floatx4 v0 = *(const floatx4*)(tp);
            floatx4 v1 = *(const floatx4*)(tp + 4);
            s0 += v0;
            s1 += v1;
        }
        tfrag[kc2] = cvt8(s0, s1);
    }

    // ---- Phase B: 16 output blocks, x frags already in registers ----
    #pragma unroll
    for (int i = 0; i < 16; ++i) {
        int nb = w * 16 + i;

        bf16x8 bfrag[4][4];
        #pragma unroll
        for (int kc = 0; kc < 4; ++kc)
            #pragma unroll
            for (int nt = 0; nt < 4; ++nt)
                bfrag[kc][nt] = *(const bf16x8*)(bp_pack +
                    (((size_t)(nb * 4 + kc) * 64 + nt * 16 + l) * 32 + q * 8));

        floatx4 acc[4];
        #pragma unroll
        for (int nt = 0; nt < 4; ++nt) {
            float bv = bias_comb[nb * 64 + nt * 16 + l];
            acc[nt][0] = bv; acc[nt][1] = bv; acc[nt][2] = bv; acc[nt][3] = bv;
        }

        #pragma unroll
        for (int kc = 0; kc < 4; ++kc) {
            bf16x8 af = (kc < 2) ? xfrag[2 * i + kc] : tfrag[kc - 2];
            #pragma unroll
            for (int nt = 0; nt < 4; ++nt)
                acc[nt] = __builtin_amdgcn_mfma_f32_16x16x32_bf16(af, bfrag[kc][nt], acc[nt], 0, 0, 0);
        }

        float* op = out + (size_t)m0 * OUT_F + nb * 64;
        #pragma unroll
        for (int nt = 0; nt < 4; ++nt)
            #pragma unroll
            for (int r = 0; r < 4; ++r)
                __builtin_nontemporal_store(acc[nt][r],
                    &op[(size_t)(q * 4 + r) * OUT_F + nt * 16 + l]);
    }
}

extern "C" void kernel_launch(void* const* d_in, const int* in_sizes, int n_in,
                              void* d_out, int out_size, void* d_ws, size_t ws_size,
                              hipStream_t stream) {
    const float* x    = (const float*)d_in[0];
    const float* diag = (const float*)d_in[1];
    const float* Wl   = (const float*)d_in[2];
    const float* Wr   = (const float*)d_in[3];
    const float* br   = (const float*)d_in[4];
    const float* bias = (const float*)d_in[5];
    float* out = (float*)d_out;

    char* ws = (char*)d_ws;
    float*          bias_comb = (float*)(ws + WS_BIAS);
    unsigned short* wl_pack   = (unsigned short*)(ws + WS_WL);
    unsigned short* bp_pack   = (unsigned short*)(ws + WS_BP);

    hipLaunchKernelGGL(prep_kernel, dim3(512), dim3(256), 0, stream,
                       diag, Wl, Wr, br, bias, bias_comb, wl_pack, bp_pack);
    // 512 wg x 4 waves; wave = (16 tokens, 1024-feature slice, 16 output blocks)
    hipLaunchKernelGGL(fused_kernel, dim3(512), dim3(256), 0, stream,
                       x, wl_pack, bp_pack, bias_comb, out);
}

// Round 3
// 274.173 us; speedup vs baseline: 1.0116x; 1.0116x over previous
//
#include <hip/hip_runtime.h>
#include <hip/hip_bf16.h>
#include <stdint.h>

// LORI_FC: out = blockdiag(x; D) + (x @ Wl^T) @ Wr^T + b_right + bias
// M=8192 tokens, IN=OUT=4096, RANK=64, 64 blocks of 64x64.
//
// R3: fuse K1+K2 -> single kernel reading x ONCE (268 MB floor ~43 us).
// R4/R5: non-temporal hints on streaming tensors (x loads, out stores).
// R6: occupancy attack. Counters showed MfmaUtil 5%, VALUBusy 10%, HBM 31%,
// Occupancy 19% -> latency-bound; grid of 512 wgs x 4 waves = 2048 waves
// caps occupancy at 25%. Restructure: 8 waves/wg (512 thr), each wave owns a
// 512-feature slice (xfrag[16] = 64 VGPRs) and 8 output blocks; t-reduce over
// 8 partials. 4096 waves -> 50% occupancy if VGPR<=128 (__launch_bounds__(512,4)).

#define M_TOT   8192
#define IN_F    4096
#define OUT_F   4096
#define RANK    64
#define NBLK    64

typedef __attribute__((ext_vector_type(8))) short  bf16x8;
typedef __attribute__((ext_vector_type(4))) float  floatx4;

// ---- ws layout (bytes) ----
#define WS_BIAS   0            // fp32[4096]                     : b_right + bias
#define WS_WL     16384        // bf16 [128 kc][64 n][32 k]      : Wl^T B-frag packed
#define WS_BP     540672       // bf16 [64 nb][4 kc][64 n][32 k] : [D;Wr^T] B-frag packed

#define S_TP 68                // t_part LDS row stride (floats); 272B = 17x16B aligned

__device__ __forceinline__ unsigned short f2bf(float f) {
    union { float f; unsigned int u; } v; v.f = f;
    unsigned int u = v.u;
    u += 0x7fffu + ((u >> 16) & 1u);   // round-to-nearest-even
    return (unsigned short)(u >> 16);
}

__device__ __forceinline__ bf16x8 cvt8(floatx4 a0, floatx4 a1) {
    bf16x8 af;
    af[0] = (short)f2bf(a0[0]); af[1] = (short)f2bf(a0[1]);
    af[2] = (short)f2bf(a0[2]); af[3] = (short)f2bf(a0[3]);
    af[4] = (short)f2bf(a1[0]); af[5] = (short)f2bf(a1[1]);
    af[6] = (short)f2bf(a1[2]); af[7] = (short)f2bf(a1[3]);
    return af;
}

// ---------------- prep: pack weights to bf16 in MFMA fragment order -------------
__global__ __launch_bounds__(256) void prep_kernel(
    const float* __restrict__ diag, const float* __restrict__ Wl,
    const float* __restrict__ Wr,   const float* __restrict__ br,
    const float* __restrict__ bias,
    float* __restrict__ bias_comb, unsigned short* __restrict__ wl_pack,
    unsigned short* __restrict__ bp_pack)
{
    int tid = blockIdx.x * blockDim.x + threadIdx.x;
    int nthr = gridDim.x * blockDim.x;

    for (int i = tid; i < OUT_F; i += nthr)
        bias_comb[i] = br[i] + bias[i];

    // Wl[n][c] -> wl_pack[((c>>5)*64 + n)*32 + (c&31)]
    for (int i = tid; i < 64 * 4096; i += nthr) {
        int n = i >> 12, c = i & 4095;
        wl_pack[((size_t)(c >> 5) * 64 + n) * 32 + (c & 31)] = f2bf(Wl[i]);
    }

    // diag[nb][k][n] -> bp_pack[((nb*4 + (k>>5))*64 + n)*32 + (k&31)]
    for (int i = tid; i < 64 * 64 * 64; i += nthr) {
        int nb = i >> 12, k = (i >> 6) & 63, n = i & 63;
        bp_pack[(((size_t)nb * 4 + (k >> 5)) * 64 + n) * 32 + (k & 31)] = f2bf(diag[i]);
    }

    // Wr[nb*64+n][r], concat-k = 64+r -> bp_pack[...]
    for (int i = tid; i < 64 * 64 * 64; i += nthr) {
        int nb = i >> 12, n = (i >> 6) & 63, r = i & 63;
        int kt = 64 + r;
        bp_pack[(((size_t)nb * 4 + (kt >> 5)) * 64 + n) * 32 + (kt & 31)] = f2bf(Wr[i]);
    }
}

// ---------------- fused: t = x@Wl^T (LDS-reduced), out = [x|t]@[D;Wr^T]+bias ----
// 512 workgroups x 8 waves. wg = 16-token m-tile; wave w owns features
// [512w, 512w+512) and output blocks [8w, 8w+8).
__global__ __launch_bounds__(512, 4) void fused_kernel(
    const float* __restrict__ x, const unsigned short* __restrict__ wl_pack,
    const unsigned short* __restrict__ bp_pack, const float* __restrict__ bias_comb,
    float* __restrict__ out)
{
    __shared__ float t_part[8 * 16 * S_TP];   // [wave][m][rank], padded

    int w = threadIdx.x >> 6;       // wave 0..7
    int lane = threadIdx.x & 63;
    int q = lane >> 4, l = lane & 15;
    int mt = blockIdx.x;            // 0..511
    int m0 = mt * 16;
    int kc_g0 = w * 16;             // this wave's first k-chunk (32 feats each)

    const float* xrow = x + (size_t)(m0 + l) * IN_F + q * 8;

    // ---- Phase A: load x slice into registers (A-frag layout), accumulate t ----
    bf16x8 xfrag[16];               // 16 tokens x 512 features bf16 = 64 VGPRs
    floatx4 tacc[4] = {};           // t partial: 16 tokens x 64 ranks

    #pragma unroll
    for (int kc = 0; kc < 16; ++kc) {
        int kc_g = kc_g0 + kc;
        const float* ap = xrow + kc_g * 32;
        floatx4 a0 = __builtin_nontemporal_load((const floatx4*)(ap));
        floatx4 a1 = __builtin_nontemporal_load((const floatx4*)(ap + 4));
        bf16x8 af = cvt8(a0, a1);
        xfrag[kc] = af;
        #pragma unroll
        for (int nt = 0; nt < 4; ++nt) {
            bf16x8 bf = *(const bf16x8*)(wl_pack + ((size_t)(kc_g * 64 + nt * 16 + l) * 32 + q * 8));
            tacc[nt] = __builtin_amdgcn_mfma_f32_16x16x32_bf16(af, bf, tacc[nt], 0, 0, 0);
        }
    }

    // write t partial to LDS: C/D layout m=q*4+r, n=nt*16+l  (2-way bank alias max)
    #pragma unroll
    for (int nt = 0; nt < 4; ++nt)
        #pragma unroll
        for (int r = 0; r < 4; ++r)
            t_part[w * 16 * S_TP + (q * 4 + r) * S_TP + nt * 16 + l] = tacc[nt][r];

    __syncthreads();

    // ---- reduce t across 8 waves, build A-frags: t[m=l][k=kc2*32+q*8+j] ----
    bf16x8 tfrag[2];
    #pragma unroll
    for (int kc2 = 0; kc2 < 2; ++kc2) {
        floatx4 s0 = {0.f, 0.f, 0.f, 0.f}, s1 = {0.f, 0.f, 0.f, 0.f};
        #pragma unroll
        for (int p = 0; p < 8; ++p) {
            const float* tp = &t_part[p * 16 * S_TP + l * S_TP + kc2 * 32 + q * 8];
            floatx4 v0 = *(const floatx4*)(tp);
            floatx4 v1 = *(const floatx4*)(tp + 4);
            s0 += v0;
            s1 += v1;
        }
        tfrag[kc2] = cvt8(s0, s1);
    }

    // ---- Phase B: 8 output blocks, x frags already in registers ----
    #pragma unroll
    for (int i = 0; i < 8; ++i) {
        int nb = w * 8 + i;

        floatx4 acc[4];
        #pragma unroll
        for (int nt = 0; nt < 4; ++nt) {
            float bv = bias_comb[nb * 64 + nt * 16 + l];
            acc[nt][0] = bv; acc[nt][1] = bv; acc[nt][2] = bv; acc[nt][3] = bv;
        }

        #pragma unroll
        for (int kc = 0; kc < 4; ++kc) {
            bf16x8 af = (kc < 2) ? xfrag[2 * i + kc] : tfrag[kc - 2];
            #pragma unroll
            for (int nt = 0; nt < 4; ++nt) {
                bf16x8 bf = *(const bf16x8*)(bp_pack +
                    (((size_t)(nb * 4 + kc) * 64 + nt * 16 + l) * 32 + q * 8));
                acc[nt] = __builtin_amdgcn_mfma_f32_16x16x32_bf16(af, bf, acc[nt], 0, 0, 0);
            }
        }

        float* op = out + (size_t)m0 * OUT_F + nb * 64;
        #pragma unroll
        for (int nt = 0; nt < 4; ++nt)
            #pragma unroll
            for (int r = 0; r < 4; ++r)
                __builtin_nontemporal_store(acc[nt][r],
                    &op[(size_t)(q * 4 + r) * OUT_F + nt * 16 + l]);
    }
}

extern "C" void kernel_launch(void* const* d_in, const int* in_sizes, int n_in,
                              void* d_out, int out_size, void* d_ws, size_t ws_size,
                              hipStream_t stream) {
    const float* x    = (const float*)d_in[0];
    const float* diag = (const float*)d_in[1];
    const float* Wl   = (const float*)d_in[2];
    const float* Wr   = (const float*)d_in[3];
    const float* br   = (const float*)d_in[4];
    const float* bias = (const float*)d_in[5];
    float* out = (float*)d_out;

    char* ws = (char*)d_ws;
    float*          bias_comb = (float*)(ws + WS_BIAS);
    unsigned short* wl_pack   = (unsigned short*)(ws + WS_WL);
    unsigned short* bp_pack   = (unsigned short*)(ws + WS_BP);

    hipLaunchKernelGGL(prep_kernel, dim3(512), dim3(256), 0, stream,
                       diag, Wl, Wr, br, bias, bias_comb, wl_pack, bp_pack);
    // 512 wg x 8 waves; wave = (16 tokens, 512-feature slice, 8 output blocks)
    hipLaunchKernelGGL(fused_kernel, dim3(512), dim3(512), 0, stream,
                       x, wl_pack, bp_pack, bias_comb, out);
}

// Round 4
// 271.614 us; speedup vs baseline: 1.0211x; 1.0094x over previous
//
#include <hip/hip_runtime.h>
#include <hip/hip_bf16.h>
#include <stdint.h>

// LORI_FC: out = blockdiag(x; D) + (x @ Wl^T) @ Wr^T + b_right + bias
// M=8192 tokens, IN=OUT=4096, RANK=64, 64 blocks of 64x64.
//
// R3: fuse K1+K2 -> single kernel reading x ONCE.
// R4/R5: non-temporal hints on streaming tensors.
// R6: 8 waves/wg -> occupancy 19->43%. Result: BW UNCHANGED at 2.5 TB/s ->
// not latency-bound; throughput cap from the access pattern itself.
// R7: store-path fix. Old stores: scalar 4B nt stores, 4 rows x 64B scattered
// segments per instr -> partial-line HBM writes (WRITE_SIZE 156MB vs 134 ideal).
// New: per block, stage acc through the wave's t_part LDS slice (free after
// the t-reduce; one extra barrier), read back row-major, store float4/lane ->
// 4 rows x 256B contiguous full-line segments, 4x fewer store instrs.

#define M_TOT   8192
#define IN_F    4096
#define OUT_F   4096
#define RANK    64
#define NBLK    64

typedef __attribute__((ext_vector_type(8))) short  bf16x8;
typedef __attribute__((ext_vector_type(4))) float  floatx4;

// ---- ws layout (bytes) ----
#define WS_BIAS   0            // fp32[4096]                     : b_right + bias
#define WS_WL     16384        // bf16 [128 kc][64 n][32 k]      : Wl^T B-frag packed
#define WS_BP     540672       // bf16 [64 nb][4 kc][64 n][32 k] : [D;Wr^T] B-frag packed

#define S_TP 68                // t_part LDS row stride (floats); 272B = 17x16B aligned

__device__ __forceinline__ unsigned short f2bf(float f) {
    union { float f; unsigned int u; } v; v.f = f;
    unsigned int u = v.u;
    u += 0x7fffu + ((u >> 16) & 1u);   // round-to-nearest-even
    return (unsigned short)(u >> 16);
}

__device__ __forceinline__ bf16x8 cvt8(floatx4 a0, floatx4 a1) {
    bf16x8 af;
    af[0] = (short)f2bf(a0[0]); af[1] = (short)f2bf(a0[1]);
    af[2] = (short)f2bf(a0[2]); af[3] = (short)f2bf(a0[3]);
    af[4] = (short)f2bf(a1[0]); af[5] = (short)f2bf(a1[1]);
    af[6] = (short)f2bf(a1[2]); af[7] = (short)f2bf(a1[3]);
    return af;
}

// ---------------- prep: pack weights to bf16 in MFMA fragment order -------------
__global__ __launch_bounds__(256) void prep_kernel(
    const float* __restrict__ diag, const float* __restrict__ Wl,
    const float* __restrict__ Wr,   const float* __restrict__ br,
    const float* __restrict__ bias,
    float* __restrict__ bias_comb, unsigned short* __restrict__ wl_pack,
    unsigned short* __restrict__ bp_pack)
{
    int tid = blockIdx.x * blockDim.x + threadIdx.x;
    int nthr = gridDim.x * blockDim.x;

    for (int i = tid; i < OUT_F; i += nthr)
        bias_comb[i] = br[i] + bias[i];

    // Wl[n][c] -> wl_pack[((c>>5)*64 + n)*32 + (c&31)]
    for (int i = tid; i < 64 * 4096; i += nthr) {
        int n = i >> 12, c = i & 4095;
        wl_pack[((size_t)(c >> 5) * 64 + n) * 32 + (c & 31)] = f2bf(Wl[i]);
    }

    // diag[nb][k][n] -> bp_pack[((nb*4 + (k>>5))*64 + n)*32 + (k&31)]
    for (int i = tid; i < 64 * 64 * 64; i += nthr) {
        int nb = i >> 12, k = (i >> 6) & 63, n = i & 63;
        bp_pack[(((size_t)nb * 4 + (k >> 5)) * 64 + n) * 32 + (k & 31)] = f2bf(diag[i]);
    }

    // Wr[nb*64+n][r], concat-k = 64+r -> bp_pack[...]
    for (int i = tid; i < 64 * 64 * 64; i += nthr) {
        int nb = i >> 12, n = (i >> 6) & 63, r = i & 63;
        int kt = 64 + r;
        bp_pack[(((size_t)nb * 4 + (kt >> 5)) * 64 + n) * 32 + (kt & 31)] = f2bf(Wr[i]);
    }
}

// ---------------- fused: t = x@Wl^T (LDS-reduced), out = [x|t]@[D;Wr^T]+bias ----
// 512 workgroups x 8 waves. wg = 16-token m-tile; wave w owns features
// [512w, 512w+512) and output blocks [8w, 8w+8).
__global__ __launch_bounds__(512, 4) void fused_kernel(
    const float* __restrict__ x, const unsigned short* __restrict__ wl_pack,
    const unsigned short* __restrict__ bp_pack, const float* __restrict__ bias_comb,
    float* __restrict__ out)
{
    __shared__ float t_part[8 * 16 * S_TP];   // [wave][m][rank], padded

    int w = threadIdx.x >> 6;       // wave 0..7
    int lane = threadIdx.x & 63;
    int q = lane >> 4, l = lane & 15;
    int mt = blockIdx.x;            // 0..511
    int m0 = mt * 16;
    int kc_g0 = w * 16;             // this wave's first k-chunk (32 feats each)

    const float* xrow = x + (size_t)(m0 + l) * IN_F + q * 8;

    // ---- Phase A: load x slice into registers (A-frag layout), accumulate t ----
    bf16x8 xfrag[16];               // 16 tokens x 512 features bf16 = 64 VGPRs
    floatx4 tacc[4] = {};           // t partial: 16 tokens x 64 ranks

    #pragma unroll
    for (int kc = 0; kc < 16; ++kc) {
        int kc_g = kc_g0 + kc;
        const float* ap = xrow + kc_g * 32;
        floatx4 a0 = __builtin_nontemporal_load((const floatx4*)(ap));
        floatx4 a1 = __builtin_nontemporal_load((const floatx4*)(ap + 4));
        bf16x8 af = cvt8(a0, a1);
        xfrag[kc] = af;
        #pragma unroll
        for (int nt = 0; nt < 4; ++nt) {
            bf16x8 bf = *(const bf16x8*)(wl_pack + ((size_t)(kc_g * 64 + nt * 16 + l) * 32 + q * 8));
            tacc[nt] = __builtin_amdgcn_mfma_f32_16x16x32_bf16(af, bf, tacc[nt], 0, 0, 0);
        }
    }

    // write t partial to LDS: C/D layout m=q*4+r, n=nt*16+l  (2-way bank alias max)
    #pragma unroll
    for (int nt = 0; nt < 4; ++nt)
        #pragma unroll
        for (int r = 0; r < 4; ++r)
            t_part[w * 16 * S_TP + (q * 4 + r) * S_TP + nt * 16 + l] = tacc[nt][r];

    __syncthreads();

    // ---- reduce t across 8 waves, build A-frags: t[m=l][k=kc2*32+q*8+j] ----
    bf16x8 tfrag[2];
    #pragma unroll
    for (int kc2 = 0; kc2 < 2; ++kc2) {
        floatx4 s0 = {0.f, 0.f, 0.f, 0.f}, s1 = {0.f, 0.f, 0.f, 0.f};
        #pragma unroll
        for (int p = 0; p < 8; ++p) {
            const float* tp = &t_part[p * 16 * S_TP + l * S_TP + kc2 * 32 + q * 8];
            floatx4 v0 = *(const floatx4*)(tp);
            floatx4 v1 = *(const floatx4*)(tp + 4);
            s0 += v0;
            s1 += v1;
        }
        tfrag[kc2] = cvt8(s0, s1);
    }

    // all waves done reading t_part -> safe to reuse as per-wave store scratch
    __syncthreads();

    float* sw = &t_part[w * 16 * S_TP];   // this wave's 16 x 68 fp32 scratch
    int hi = lane >> 4, lo = lane & 15;

    // ---- Phase B: 8 output blocks, x frags already in registers ----
    #pragma unroll
    for (int i = 0; i < 8; ++i) {
        int nb = w * 8 + i;

        floatx4 acc[4];
        #pragma unroll
        for (int nt = 0; nt < 4; ++nt) {
            float bv = bias_comb[nb * 64 + nt * 16 + l];
            acc[nt][0] = bv; acc[nt][1] = bv; acc[nt][2] = bv; acc[nt][3] = bv;
        }

        #pragma unroll
        for (int kc = 0; kc < 4; ++kc) {
            bf16x8 af = (kc < 2) ? xfrag[2 * i + kc] : tfrag[kc - 2];
            #pragma unroll
            for (int nt = 0; nt < 4; ++nt) {
                bf16x8 bf = *(const bf16x8*)(bp_pack +
                    (((size_t)(nb * 4 + kc) * 64 + nt * 16 + l) * 32 + q * 8));
                acc[nt] = __builtin_amdgcn_mfma_f32_16x16x32_bf16(af, bf, acc[nt], 0, 0, 0);
            }
        }

        // stage C/D-layout acc into LDS (private slice; same-wave dep only)
        #pragma unroll
        for (int nt = 0; nt < 4; ++nt)
            #pragma unroll
            for (int r = 0; r < 4; ++r)
                sw[(q * 4 + r) * S_TP + nt * 16 + l] = acc[nt][r];

        // read back row-major, store 16B/lane: 4 rows x 256B full-line segments
        #pragma unroll
        for (int c = 0; c < 4; ++c) {
            int row = c * 4 + hi;
            floatx4 v = *(const floatx4*)&sw[row * S_TP + lo * 4];
            __builtin_nontemporal_store(v,
                (floatx4*)(out + (size_t)(m0 + row) * OUT_F + nb * 64 + lo * 4));
        }
    }
}

extern "C" void kernel_launch(void* const* d_in, const int* in_sizes, int n_in,
                              void* d_out, int out_size, void* d_ws, size_t ws_size,
                              hipStream_t stream) {
    const float* x    = (const float*)d_in[0];
    const float* diag = (const float*)d_in[1];
    const float* Wl   = (const float*)d_in[2];
    const float* Wr   = (const float*)d_in[3];
    const float* br   = (const float*)d_in[4];
    const float* bias = (const float*)d_in[5];
    float* out = (float*)d_out;

    char* ws = (char*)d_ws;
    float*          bias_comb = (float*)(ws + WS_BIAS);
    unsigned short* wl_pack   = (unsigned short*)(ws + WS_WL);
    unsigned short* bp_pack   = (unsigned short*)(ws + WS_BP);

    hipLaunchKernelGGL(prep_kernel, dim3(512), dim3(256), 0, stream,
                       diag, Wl, Wr, br, bias, bias_comb, wl_pack, bp_pack);
    // 512 wg x 8 waves; wave = (16 tokens, 512-feature slice, 8 output blocks)
    hipLaunchKernelGGL(fused_kernel, dim3(512), dim3(512), 0, stream,
                       x, wl_pack, bp_pack, bias_comb, out);
}

// Round 6
// 268.516 us; speedup vs baseline: 1.0329x; 1.0115x over previous
//
#include <hip/hip_runtime.h>
#include <hip/hip_bf16.h>
#include <stdint.h>

// LORI_FC: out = blockdiag(x; D) + (x @ Wl^T) @ Wr^T + b_right + bias
// M=8192 tokens, IN=OUT=4096, RANK=64, 64 blocks of 64x64.
//
// R3: fuse K1+K2 -> single kernel reading x ONCE.
// R4/R5: non-temporal hints on streaming tensors.
// R6: 8 waves/wg -> occupancy 19->43%. BW UNCHANGED 2.5 TB/s.
// R7: full-line vectorized stores via LDS staging. WRITE_SIZE 156->131 MB
//     (ideal), dur 93->87.7 us. BW still ~2.4 TB/s.
// R8: request-rate theory. All weight loads had lane-scattered addresses
// (consecutive lanes 64B+ apart -> ~64 separate 64B requests per wave-load;
// per-CU MSHR budget caps device BW at ~2.4 TB/s independent of occupancy).
// Fix: repack wl/bp LANE-MAJOR -> every weight load is one contiguous
// aligned 1KB wave burst. Same per-lane data (pure address permutation).
// R9: resubmit of R8 (round 5 was an infra failure, no counters).

#define M_TOT   8192
#define IN_F    4096
#define OUT_F   4096
#define RANK    64
#define NBLK    64

typedef __attribute__((ext_vector_type(8))) short  bf16x8;
typedef __attribute__((ext_vector_type(4))) float  floatx4;

// ---- ws layout (bytes) ----
#define WS_BIAS   0            // fp32[4096]                       : b_right + bias
#define WS_WL     16384        // bf16 [128 kc][4 nt][64 lane][8]  : Wl^T B-frag, lane-major
#define WS_BP     540672       // bf16 [64 nb][4 kc][4 nt][64 lane][8] : [D;Wr^T], lane-major

#define S_TP 68                // t_part LDS row stride (floats); 272B = 17x16B aligned

__device__ __forceinline__ unsigned short f2bf(float f) {
    union { float f; unsigned int u; } v; v.f = f;
    unsigned int u = v.u;
    u += 0x7fffu + ((u >> 16) & 1u);   // round-to-nearest-even
    return (unsigned short)(u >> 16);
}

__device__ __forceinline__ bf16x8 cvt8(floatx4 a0, floatx4 a1) {
    bf16x8 af;
    af[0] = (short)f2bf(a0[0]); af[1] = (short)f2bf(a0[1]);
    af[2] = (short)f2bf(a0[2]); af[3] = (short)f2bf(a0[3]);
    af[4] = (short)f2bf(a1[0]); af[5] = (short)f2bf(a1[1]);
    af[6] = (short)f2bf(a1[2]); af[7] = (short)f2bf(a1[3]);
    return af;
}

// ---------------- prep: pack weights to bf16, lane-major fragment order --------
// Fragment consumer: lane = q*16+l reads 8 shorts; lane's data for (kc,nt) is
// B[n = nt*16+l][k = kc*32 + q*8 + j]. Lane-major: frag block base + lane*8.
__global__ __launch_bounds__(256) void prep_kernel(
    const float* __restrict__ diag, const float* __restrict__ Wl,
    const float* __restrict__ Wr,   const float* __restrict__ br,
    const float* __restrict__ bias,
    float* __restrict__ bias_comb, unsigned short* __restrict__ wl_pack,
    unsigned short* __restrict__ bp_pack)
{
    int tid = blockIdx.x * blockDim.x + threadIdx.x;
    int nthr = gridDim.x * blockDim.x;

    for (int i = tid; i < OUT_F; i += nthr)
        bias_comb[i] = br[i] + bias[i];

    // Wl[n][c]: kc=c>>5, q=(c>>3)&3, j=c&7, nt=n>>4, l=n&15
    // -> wl_pack[(((kc*4)+nt)*64 + q*16+l)*8 + j]
    for (int i = tid; i < 64 * 4096; i += nthr) {
        int n = i >> 12, c = i & 4095;
        wl_pack[(((size_t)(c >> 5) * 4 + (n >> 4)) * 64
                 + ((c >> 3) & 3) * 16 + (n & 15)) * 8 + (c & 7)] = f2bf(Wl[i]);
    }

    // diag[nb][k][n]: concat-k = k (kc = k>>5 in {0,1})
    for (int i = tid; i < 64 * 64 * 64; i += nthr) {
        int nb = i >> 12, k = (i >> 6) & 63, n = i & 63;
        bp_pack[((((size_t)nb * 4 + (k >> 5)) * 4 + (n >> 4)) * 64
                 + ((k >> 3) & 3) * 16 + (n & 15)) * 8 + (k & 7)] = f2bf(diag[i]);
    }

    // Wr[nb*64+n][r]: concat-k = 64+r (kc = 2+(r>>5)); q=(r>>3)&3, j=r&7
    for (int i = tid; i < 64 * 64 * 64; i += nthr) {
        int nb = i >> 12, n = (i >> 6) & 63, r = i & 63;
        bp_pack[((((size_t)nb * 4 + 2 + (r >> 5)) * 4 + (n >> 4)) * 64
                 + ((r >> 3) & 3) * 16 + (n & 15)) * 8 + (r & 7)] = f2bf(Wr[i]);
    }
}

// ---------------- fused: t = x@Wl^T (LDS-reduced), out = [x|t]@[D;Wr^T]+bias ----
// 512 workgroups x 8 waves. wg = 16-token m-tile; wave w owns features
// [512w, 512w+512) and output blocks [8w, 8w+8).
__global__ __launch_bounds__(512, 4) void fused_kernel(
    const float* __restrict__ x, const unsigned short* __restrict__ wl_pack,
    const unsigned short* __restrict__ bp_pack, const float* __restrict__ bias_comb,
    float* __restrict__ out)
{
    __shared__ float t_part[8 * 16 * S_TP];   // [wave][m][rank], padded

    int w = threadIdx.x >> 6;       // wave 0..7
    int lane = threadIdx.x & 63;
    int q = lane >> 4, l = lane & 15;
    int mt = blockIdx.x;            // 0..511
    int m0 = mt * 16;
    int kc_g0 = w * 16;             // this wave's first k-chunk (32 feats each)

    const float* xrow = x + (size_t)(m0 + l) * IN_F + q * 8;

    // ---- Phase A: load x slice into registers (A-frag layout), accumulate t ----
    bf16x8 xfrag[16];               // 16 tokens x 512 features bf16 = 64 VGPRs
    floatx4 tacc[4] = {};           // t partial: 16 tokens x 64 ranks

    #pragma unroll
    for (int kc = 0; kc < 16; ++kc) {
        int kc_g = kc_g0 + kc;
        const float* ap = xrow + kc_g * 32;
        floatx4 a0 = __builtin_nontemporal_load((const floatx4*)(ap));
        floatx4 a1 = __builtin_nontemporal_load((const floatx4*)(ap + 4));
        bf16x8 af = cvt8(a0, a1);
        xfrag[kc] = af;
        #pragma unroll
        for (int nt = 0; nt < 4; ++nt) {
            // lane-major: contiguous 1KB per (kc,nt) frag block
            bf16x8 bf = *(const bf16x8*)(wl_pack +
                (((size_t)kc_g * 4 + nt) * 64 + lane) * 8);
            tacc[nt] = __builtin_amdgcn_mfma_f32_16x16x32_bf16(af, bf, tacc[nt], 0, 0, 0);
        }
    }

    // write t partial to LDS: C/D layout m=q*4+r, n=nt*16+l  (2-way bank alias max)
    #pragma unroll
    for (int nt = 0; nt < 4; ++nt)
        #pragma unroll
        for (int r = 0; r < 4; ++r)
            t_part[w * 16 * S_TP + (q * 4 + r) * S_TP + nt * 16 + l] = tacc[nt][r];

    __syncthreads();

    // ---- reduce t across 8 waves, build A-frags: t[m=l][k=kc2*32+q*8+j] ----
    bf16x8 tfrag[2];
    #pragma unroll
    for (int kc2 = 0; kc2 < 2; ++kc2) {
        floatx4 s0 = {0.f, 0.f, 0.f, 0.f}, s1 = {0.f, 0.f, 0.f, 0.f};
        #pragma unroll
        for (int p = 0; p < 8; ++p) {
            const float* tp = &t_part[p * 16 * S_TP + l * S_TP + kc2 * 32 + q * 8];
            floatx4 v0 = *(const floatx4*)(tp);
            floatx4 v1 = *(const floatx4*)(tp + 4);
            s0 += v0;
            s1 += v1;
        }
        tfrag[kc2] = cvt8(s0, s1);
    }

    // all waves done reading t_part -> safe to reuse as per-wave store scratch
    __syncthreads();

    float* sw = &t_part[w * 16 * S_TP];   // this wave's 16 x 68 fp32 scratch
    int hi = lane >> 4, lo = lane & 15;

    // ---- Phase B: 8 output blocks, x frags already in registers ----
    #pragma unroll
    for (int i = 0; i < 8; ++i) {
        int nb = w * 8 + i;

        floatx4 acc[4];
        #pragma unroll
        for (int nt = 0; nt < 4; ++nt) {
            float bv = bias_comb[nb * 64 + nt * 16 + l];
            acc[nt][0] = bv; acc[nt][1] = bv; acc[nt][2] = bv; acc[nt][3] = bv;
        }

        #pragma unroll
        for (int kc = 0; kc < 4; ++kc) {
            bf16x8 af = (kc < 2) ? xfrag[2 * i + kc] : tfrag[kc - 2];
            #pragma unroll
            for (int nt = 0; nt < 4; ++nt) {
                bf16x8 bf = *(const bf16x8*)(bp_pack +
                    ((((size_t)nb * 4 + kc) * 4 + nt) * 64 + lane) * 8);
                acc[nt] = __builtin_amdgcn_mfma_f32_16x16x32_bf16(af, bf, acc[nt], 0, 0, 0);
            }
        }

        // stage C/D-layout acc into LDS (private slice; same-wave dep only)
        #pragma unroll
        for (int nt = 0; nt < 4; ++nt)
            #pragma unroll
            for (int r = 0; r < 4; ++r)
                sw[(q * 4 + r) * S_TP + nt * 16 + l] = acc[nt][r];

        // read back row-major, store 16B/lane: 4 rows x 256B full-line segments
        #pragma unroll
        for (int c = 0; c < 4; ++c) {
            int row = c * 4 + hi;
            floatx4 v = *(const floatx4*)&sw[row * S_TP + lo * 4];
            __builtin_nontemporal_store(v,
                (floatx4*)(out + (size_t)(m0 + row) * OUT_F + nb * 64 + lo * 4));
        }
    }
}

extern "C" void kernel_launch(void* const* d_in, const int* in_sizes, int n_in,
                              void* d_out, int out_size, void* d_ws, size_t ws_size,
                              hipStream_t stream) {
    const float* x    = (const float*)d_in[0];
    const float* diag = (const float*)d_in[1];
    const float* Wl   = (const float*)d_in[2];
    const float* Wr   = (const float*)d_in[3];
    const float* br   = (const float*)d_in[4];
    const float* bias = (const float*)d_in[5];
    float* out = (float*)d_out;

    char* ws = (char*)d_ws;
    float*          bias_comb = (float*)(ws + WS_BIAS);
    unsigned short* wl_pack   = (unsigned short*)(ws + WS_WL);
    unsigned short* bp_pack   = (unsigned short*)(ws + WS_BP);

    hipLaunchKernelGGL(prep_kernel, dim3(512), dim3(256), 0, stream,
                       diag, Wl, Wr, br, bias, bias_comb, wl_pack, bp_pack);
    // 512 wg x 8 waves; wave = (16 tokens, 512-feature slice, 8 output blocks)
    hipLaunchKernelGGL(fused_kernel, dim3(512), dim3(512), 0, stream,
                       x, wl_pack, bp_pack, bias_comb, out);
}

// Round 7
// 267.137 us; speedup vs baseline: 1.0382x; 1.0052x over previous
//
#include <hip/hip_runtime.h>
#include <hip/hip_bf16.h>
#include <stdint.h>

// LORI_FC: out = blockdiag(x; D) + (x @ Wl^T) @ Wr^T + b_right + bias
// M=8192 tokens, IN=OUT=4096, RANK=64, 64 blocks of 64x64.
//
// R3: fuse K1+K2 -> single kernel reading x ONCE.
// R6: 8 waves/wg, occupancy 19->43%: BW unchanged -> not latency-bound.
// R7: full-line stores (WRITE 156->131MB ideal): dur 93->88.
// R8/R9: lane-major weight repack (1KB contiguous wave bursts): dur 88->84.
// R10: weight-reuse attack. The dominant traffic is INVISIBLE to FETCH_SIZE:
// each wg reads 4.5 MB of packed weights from L2/L3 (9x its 512 KB stream
// traffic); 512 wgs -> 2.3 GB of cache reads ~ 67 us at L2 ceiling = the
// observed 84 us wall. Fix: 32 tokens/wg (256 wgs) -> weight traffic halves;
// each Phase-B weight fragment now feeds TWO m-halves (xfrag[2][16]).

#define M_TOT   8192
#define IN_F    4096
#define OUT_F   4096
#define RANK    64
#define NBLK    64

typedef __attribute__((ext_vector_type(8))) short  bf16x8;
typedef __attribute__((ext_vector_type(4))) float  floatx4;

// ---- ws layout (bytes) ----
#define WS_BIAS   0            // fp32[4096]                       : b_right + bias
#define WS_WL     16384        // bf16 [128 kc][4 nt][64 lane][8]  : Wl^T B-frag, lane-major
#define WS_BP     540672       // bf16 [64 nb][4 kc][4 nt][64 lane][8] : [D;Wr^T], lane-major

#define S_TP 68                // t_part LDS row stride (floats); 272B = 17x16B aligned

__device__ __forceinline__ unsigned short f2bf(float f) {
    union { float f; unsigned int u; } v; v.f = f;
    unsigned int u = v.u;
    u += 0x7fffu + ((u >> 16) & 1u);   // round-to-nearest-even
    return (unsigned short)(u >> 16);
}

__device__ __forceinline__ bf16x8 cvt8(floatx4 a0, floatx4 a1) {
    bf16x8 af;
    af[0] = (short)f2bf(a0[0]); af[1] = (short)f2bf(a0[1]);
    af[2] = (short)f2bf(a0[2]); af[3] = (short)f2bf(a0[3]);
    af[4] = (short)f2bf(a1[0]); af[5] = (short)f2bf(a1[1]);
    af[6] = (short)f2bf(a1[2]); af[7] = (short)f2bf(a1[3]);
    return af;
}

// ---------------- prep: pack weights to bf16, lane-major fragment order --------
// Fragment consumer: lane = q*16+l reads 8 shorts; lane's data for (kc,nt) is
// B[n = nt*16+l][k = kc*32 + q*8 + j]. Lane-major: frag block base + lane*8.
__global__ __launch_bounds__(256) void prep_kernel(
    const float* __restrict__ diag, const float* __restrict__ Wl,
    const float* __restrict__ Wr,   const float* __restrict__ br,
    const float* __restrict__ bias,
    float* __restrict__ bias_comb, unsigned short* __restrict__ wl_pack,
    unsigned short* __restrict__ bp_pack)
{
    int tid = blockIdx.x * blockDim.x + threadIdx.x;
    int nthr = gridDim.x * blockDim.x;

    for (int i = tid; i < OUT_F; i += nthr)
        bias_comb[i] = br[i] + bias[i];

    // Wl[n][c]: kc=c>>5, q=(c>>3)&3, j=c&7, nt=n>>4, l=n&15
    // -> wl_pack[(((kc*4)+nt)*64 + q*16+l)*8 + j]
    for (int i = tid; i < 64 * 4096; i += nthr) {
        int n = i >> 12, c = i & 4095;
        wl_pack[(((size_t)(c >> 5) * 4 + (n >> 4)) * 64
                 + ((c >> 3) & 3) * 16 + (n & 15)) * 8 + (c & 7)] = f2bf(Wl[i]);
    }

    // diag[nb][k][n]: concat-k = k (kc = k>>5 in {0,1})
    for (int i = tid; i < 64 * 64 * 64; i += nthr) {
        int nb = i >> 12, k = (i >> 6) & 63, n = i & 63;
        bp_pack[((((size_t)nb * 4 + (k >> 5)) * 4 + (n >> 4)) * 64
                 + ((k >> 3) & 3) * 16 + (n & 15)) * 8 + (k & 7)] = f2bf(diag[i]);
    }

    // Wr[nb*64+n][r]: concat-k = 64+r (kc = 2+(r>>5)); q=(r>>3)&3, j=r&7
    for (int i = tid; i < 64 * 64 * 64; i += nthr) {
        int nb = i >> 12, n = (i >> 6) & 63, r = i & 63;
        bp_pack[((((size_t)nb * 4 + 2 + (r >> 5)) * 4 + (n >> 4)) * 64
                 + ((r >> 3) & 3) * 16 + (n & 15)) * 8 + (r & 7)] = f2bf(Wr[i]);
    }
}

// ---------------- fused: t = x@Wl^T (LDS-reduced), out = [x|t]@[D;Wr^T]+bias ----
// 256 workgroups x 8 waves. wg = 32-token m-tile (2 halves of 16); wave w owns
// features [512w, 512w+512) and output blocks [8w, 8w+8).
__global__ __launch_bounds__(512, 2) void fused_kernel(
    const float* __restrict__ x, const unsigned short* __restrict__ wl_pack,
    const unsigned short* __restrict__ bp_pack, const float* __restrict__ bias_comb,
    float* __restrict__ out)
{
    __shared__ float t_part[8 * 32 * S_TP];   // [wave][m=32][rank], padded

    int w = threadIdx.x >> 6;       // wave 0..7
    int lane = threadIdx.x & 63;
    int q = lane >> 4, l = lane & 15;
    int mt = blockIdx.x;            // 0..255
    int m0 = mt * 32;
    int kc_g0 = w * 16;             // this wave's first k-chunk (32 feats each)

    // ---- Phase A: load x (2 m-halves) into registers, accumulate t ----
    bf16x8 xfrag[2][16];            // 32 tokens x 512 features bf16 = 128 VGPRs
    floatx4 tacc[2][4] = {};        // t partial: 32 tokens x 64 ranks

    #pragma unroll
    for (int kc = 0; kc < 16; ++kc) {
        int kc_g = kc_g0 + kc;
        bf16x8 bfw[4];
        #pragma unroll
        for (int nt = 0; nt < 4; ++nt)   // lane-major: contiguous 1KB per frag
            bfw[nt] = *(const bf16x8*)(wl_pack +
                (((size_t)kc_g * 4 + nt) * 64 + lane) * 8);

        #pragma unroll
        for (int h = 0; h < 2; ++h) {
            const float* ap = x + (size_t)(m0 + h * 16 + l) * IN_F + q * 8 + kc_g * 32;
            floatx4 a0 = __builtin_nontemporal_load((const floatx4*)(ap));
            floatx4 a1 = __builtin_nontemporal_load((const floatx4*)(ap + 4));
            bf16x8 af = cvt8(a0, a1);
            xfrag[h][kc] = af;
            #pragma unroll
            for (int nt = 0; nt < 4; ++nt)
                tacc[h][nt] = __builtin_amdgcn_mfma_f32_16x16x32_bf16(af, bfw[nt], tacc[h][nt], 0, 0, 0);
        }
    }

    // write t partial to LDS: C/D layout m=h*16+q*4+r, n=nt*16+l
    #pragma unroll
    for (int h = 0; h < 2; ++h)
        #pragma unroll
        for (int nt = 0; nt < 4; ++nt)
            #pragma unroll
            for (int r = 0; r < 4; ++r)
                t_part[(w * 32 + h * 16 + q * 4 + r) * S_TP + nt * 16 + l] = tacc[h][nt][r];

    __syncthreads();

    // ---- reduce t across 8 waves, build A-frags per half: t[m=h*16+l][k] ----
    bf16x8 tfrag[2][2];
    #pragma unroll
    for (int h = 0; h < 2; ++h)
        #pragma unroll
        for (int kc2 = 0; kc2 < 2; ++kc2) {
            floatx4 s0 = {0.f, 0.f, 0.f, 0.f}, s1 = {0.f, 0.f, 0.f, 0.f};
            #pragma unroll
            for (int p = 0; p < 8; ++p) {
                const float* tp = &t_part[(p * 32 + h * 16 + l) * S_TP + kc2 * 32 + q * 8];
                floatx4 v0 = *(const floatx4*)(tp);
                floatx4 v1 = *(const floatx4*)(tp + 4);
                s0 += v0;
                s1 += v1;
            }
            tfrag[h][kc2] = cvt8(s0, s1);
        }

    // all waves done reading t_part -> safe to reuse as per-wave store scratch
    __syncthreads();

    float* sw = &t_part[w * 32 * S_TP];   // this wave's 32 x 68 fp32 scratch
    int hi = lane >> 4, lo = lane & 15;

    // ---- Phase B: 8 output blocks; weight frags reused across both m-halves ----
    #pragma unroll
    for (int i = 0; i < 8; ++i) {
        int nb = w * 8 + i;

        floatx4 acc[2][4];
        #pragma unroll
        for (int nt = 0; nt < 4; ++nt) {
            float bv = bias_comb[nb * 64 + nt * 16 + l];
            #pragma unroll
            for (int h = 0; h < 2; ++h) {
                acc[h][nt][0] = bv; acc[h][nt][1] = bv;
                acc[h][nt][2] = bv; acc[h][nt][3] = bv;
            }
        }

        #pragma unroll
        for (int kc = 0; kc < 4; ++kc) {
            #pragma unroll
            for (int nt = 0; nt < 4; ++nt) {
                bf16x8 bf = *(const bf16x8*)(bp_pack +
                    ((((size_t)nb * 4 + kc) * 4 + nt) * 64 + lane) * 8);
                #pragma unroll
                for (int h = 0; h < 2; ++h) {
                    bf16x8 af = (kc < 2) ? xfrag[h][2 * i + kc] : tfrag[h][kc - 2];
                    acc[h][nt] = __builtin_amdgcn_mfma_f32_16x16x32_bf16(af, bf, acc[h][nt], 0, 0, 0);
                }
            }
        }

        // stage C/D-layout acc into LDS (private slice; same-wave dep only)
        #pragma unroll
        for (int h = 0; h < 2; ++h)
            #pragma unroll
            for (int nt = 0; nt < 4; ++nt)
                #pragma unroll
                for (int r = 0; r < 4; ++r)
                    sw[(h * 16 + q * 4 + r) * S_TP + nt * 16 + l] = acc[h][nt][r];

        // read back row-major, store 16B/lane: 4 rows x 256B full-line segments
        #pragma unroll
        for (int c = 0; c < 8; ++c) {
            int row = c * 4 + hi;
            floatx4 v = *(const floatx4*)&sw[row * S_TP + lo * 4];
            __builtin_nontemporal_store(v,
                (floatx4*)(out + (size_t)(m0 + row) * OUT_F + nb * 64 + lo * 4));
        }
    }
}

extern "C" void kernel_launch(void* const* d_in, const int* in_sizes, int n_in,
                              void* d_out, int out_size, void* d_ws, size_t ws_size,
                              hipStream_t stream) {
    const float* x    = (const float*)d_in[0];
    const float* diag = (const float*)d_in[1];
    const float* Wl   = (const float*)d_in[2];
    const float* Wr   = (const float*)d_in[3];
    const float* br   = (const float*)d_in[4];
    const float* bias = (const float*)d_in[5];
    float* out = (float*)d_out;

    char* ws = (char*)d_ws;
    float*          bias_comb = (float*)(ws + WS_BIAS);
    unsigned short* wl_pack   = (unsigned short*)(ws + WS_WL);
    unsigned short* bp_pack   = (unsigned short*)(ws + WS_BP);

    hipLaunchKernelGGL(prep_kernel, dim3(512), dim3(256), 0, stream,
                       diag, Wl, Wr, br, bias, bias_comb, wl_pack, bp_pack);
    // 256 wg x 8 waves; wave = (32 tokens, 512-feature slice, 8 output blocks)
    hipLaunchKernelGGL(fused_kernel, dim3(256), dim3(512), 0, stream,
                       x, wl_pack, bp_pack, bias_comb, out);
}